// Round 5
// baseline (578.284 us; speedup 1.0000x reference)
//
#include <hip/hip_runtime.h>

// CapsuleLinear dynamic routing via bf16 hi/lo MFMA. N=64, I=256, O=128, K=16, L=32.
//
// Round 15 = R14's named-register rotation, slimmed to fit 128 VGPRs.
//   R14 (4 named buffers = 64 frag VGPRs) needed ~145 arch-VGPRs -> 124MB
//   residual spill, main 131us. The named-buffer approach itself worked
//   (no array demotion); just over budget. Now: THREE named buffers
//   FA/FB/FC (48 frag VGPRs), rotation s -> s%3, prefetch distance 2 steps
//   (~400cy), everything compile-time indexed via full unroll.
//   FP accumulation order identical to R10/R14 (even i -> Pa, odd -> Pb,
//   each ascending; softsteps strictly ascending i).
//   Expected ~100-115 VGPRs -> no spill (gate: WRITE_SIZE back to ~1MiB).

#define ICAPS 256
#define OCAPS 128
#define WS_XC 67108864ull
#define WS_NEED 68157440ull
#define KPAD 20

typedef __attribute__((ext_vector_type(8))) short s16x8;
typedef __attribute__((ext_vector_type(16))) float f32x16;

union u4s8 { unsigned u[4]; s16x8 v; };

__device__ inline unsigned rne_adj(unsigned u) {       // bits + RNE increment
    return u + 0x7FFFu + ((u >> 16) & 1u);
}

// RNE hi/lo split of 8 fp32 -> two packed s16x8 (bf16 pairs), R4/R6 numerics.
__device__ inline void split8(const float* f, s16x8& hi, s16x8& lo) {
    u4s8 H, L;
    #pragma unroll
    for (int c = 0; c < 4; ++c) {
        const unsigned u0 = __float_as_uint(f[2 * c]);
        const unsigned u1 = __float_as_uint(f[2 * c + 1]);
        const unsigned r0 = rne_adj(u0), r1 = rne_adj(u1);
        H.u[c] = __builtin_amdgcn_perm(r1, r0, 0x07060302u);   // {hi16(r1),hi16(r0)}
        const float h0 = __uint_as_float(r0 & 0xFFFF0000u);
        const float h1 = __uint_as_float(r1 & 0xFFFF0000u);
        const unsigned l0 = rne_adj(__float_as_uint(f[2 * c] - h0));      // exact resid
        const unsigned l1 = rne_adj(__float_as_uint(f[2 * c + 1] - h1));  // then RNE
        L.u[c] = __builtin_amdgcn_perm(l1, l0, 0x07060302u);
    }
    hi = H.v; lo = L.v;
}

// ---------------- prep: coalesced read + LDS transpose + split ----------------
// w tiles: gid 0..32767 (= o*256+i); x tiles: gid 32768..33279 (= nh*256+i).
__global__ __launch_bounds__(512)
void caps_prep(const float* __restrict__ x, const float* __restrict__ w,
               unsigned char* __restrict__ ws) {
    __shared__ float T[8][32 * KPAD];     // per-wave 2.5 KB transpose buffer
    const int wv = threadIdx.x >> 6, lane = threadIdx.x & 63;
    const int gid = blockIdx.x * 8 + wv;
    float f[8];
    s16x8 hi, lo;

    if (gid < 32768) {
        // coalesced: wave reads its whole 2KB tile (512 floats) contiguously
        const float* src = w + (size_t)gid * 512 + lane * 8;
        const float4 a = *(const float4*)src;
        const float4 b = *(const float4*)(src + 4);
        const float v[8] = {a.x, a.y, a.z, a.w, b.x, b.y, b.z, b.w};
        // element j: k = lane>>2 (const), l = (lane&3)*8 + j  -> T[l][k]
        {
            float* Tw = &T[wv][0];
            const int k = lane >> 2, l0 = (lane & 3) * 8;
            #pragma unroll
            for (int j = 0; j < 8; ++j) Tw[(l0 + j) * KPAD + k] = v[j];
        }
        // T is strictly per-wave: a wave-local LDS drain suffices (no barrier).
        asm volatile("s_waitcnt lgkmcnt(0)" ::: "memory");
        // fragment read: l = lane&31, k = kb..kb+7 (contiguous -> 2x b128)
        {
            const float* rd = &T[wv][(lane & 31) * KPAD + (lane >> 5) * 8];
            const float4 ra = *(const float4*)rd;
            const float4 rb = *(const float4*)(rd + 4);
            f[0] = ra.x; f[1] = ra.y; f[2] = ra.z; f[3] = ra.w;
            f[4] = rb.x; f[5] = rb.y; f[6] = rb.z; f[7] = rb.w;
        }
        split8(f, hi, lo);
        s16x8* WC = (s16x8*)ws;
        WC[(size_t)gid * 128 + lane] = hi;        // 1KB coalesced
        WC[(size_t)gid * 128 + 64 + lane] = lo;   // 1KB coalesced
    } else if (gid < 33280) {
        const int id = gid - 32768;
        const int nh = id >> 8, i = id & 255;
        const int n = lane & 31, kb = (lane >> 5) * 8;
        const float* src = x + ((size_t)(nh * 32 + n) * ICAPS + i) * 16 + kb;
        const float4 a = *(const float4*)src;
        const float4 b = *(const float4*)(src + 4);
        f[0] = a.x; f[1] = a.y; f[2] = a.z; f[3] = a.w;
        f[4] = b.x; f[5] = b.y; f[6] = b.z; f[7] = b.w;
        split8(f, hi, lo);
        s16x8* XC = (s16x8*)(ws + WS_XC);
        XC[(size_t)id * 128 + lane] = hi;
        XC[(size_t)id * 128 + 64 + lane] = lo;
    }
}

// ---------------- main: MFMA routing, 8 waves, 3-named-buffer rotation ----------------

#define MF(a, b, c) __builtin_amdgcn_mfma_f32_32x32x16_bf16(a, b, c, 0, 0, 0)

// load ONE i-tile (4 s16x8 records = 16 VGPRs) into named regs N0..N3.
// N0 = W hi, N1 = W lo, N2 = X hi, N3 = X lo.
#define LD1(N, ii)                                   \
    {                                                \
        const size_t b_ = (size_t)(ii) * 128;        \
        N##0 = Wp[b_]; N##1 = Wp[b_ + 64];           \
        N##2 = Xp[b_]; N##3 = Xp[b_ + 64];           \
    }

// 3-MFMA triple product for one i (order identical to R10: al*bh, ah*bl, ah*bh)
#define TRIP(N, ACC)                 \
    {                                \
        ACC = MF(N##1, N##2, ACC);   \
        ACC = MF(N##0, N##3, ACC);   \
        ACC = MF(N##0, N##2, ACC);   \
    }

#define SOFTSTEP(P, ii)                                                   \
    {                                                                     \
        float da = P[0] * vr[0], db = P[8] * vr[8];                       \
        _Pragma("unroll")                                                 \
        for (int r = 1; r < 8; ++r) {                                     \
            da = fmaf(P[r], vr[r], da);                                   \
            db = fmaf(P[r + 8], vr[r + 8], db);                           \
        }                                                                 \
        float d = da + db;                                                \
        d += __shfl_xor(d, 32);                /* combine l-halves */     \
        if (pass == 1) {                                                  \
            if (half == 0) lg[(ii) * 32 + n] = d;                         \
        } else {                                                          \
            d += lg[(ii) * 32 + n];                                       \
        }                                                                 \
        const float e = __expf(d);                                        \
        z += e;                                                           \
        _Pragma("unroll")                                                 \
        for (int r = 0; r < 16; ++r) uacc[r] = fmaf(e, P[r], uacc[r]);    \
    }

// one pass>=1 step: fresh P, triple product, softmax-accumulate
#define PROC1(N, ii)                 \
    {                                \
        f32x16 P = {};               \
        TRIP(N, P);                  \
        SOFTSTEP(P, ii);             \
    }

__global__ __launch_bounds__(512)
void caps_main(const unsigned char* __restrict__ ws, float* __restrict__ out) {
    __shared__ float lg[ICAPS * 32];      // [i][n] 32 KB
    __shared__ float slab[8 * 1280];      // per-wave u partials (lane stride 20)
    __shared__ float svv[32 * 33];        // s then v
    __shared__ float zz[8 * 32];
    __shared__ float zinv[32];

    const int t = threadIdx.x, wv = t >> 6, lane = t & 63;
    const int o = blockIdx.x & 127, nh = blockIdx.x >> 7;   // o-pairs share an XCD
    const int n = lane & 31, half = lane >> 5;

    // block layout: per tile 128 s16x8 records; hi at +lane, lo at +64+lane
    const s16x8* Wp = (const s16x8*)ws + (size_t)o * ICAPS * 128 + lane;
    const s16x8* Xp = (const s16x8*)(ws + WS_XC) + (size_t)nh * ICAPS * 128 + lane;

    float vr[16];
    const int ibase = wv * 32;            // 32 i per wave = 32 steps of 1 i-tile

    // three individually-NAMED rotation buffers (16 VGPRs each; never
    // array-indexed -> guaranteed register allocation, no scratch)
    s16x8 FA0, FA1, FA2, FA3;
    s16x8 FB0, FB1, FB2, FB3;
    s16x8 FC0, FC1, FC2, FC3;

    // prologue for pass 0 (subsequent passes prefetch before the reduction)
    LD1(FA, ibase + 0);
    LD1(FB, ibase + 1);
    LD1(FC, ibase + 2);

    for (int pass = 0; pass < 3; ++pass) {
        float uacc[16];
        #pragma unroll
        for (int r = 0; r < 16; ++r) uacc[r] = 0.f;
        float z = 0.f;

        if (pass == 0) {
            f32x16 Pa = {}, Pb = {};
            #pragma unroll
            for (int g = 0; g < 9; ++g) {            // s = 3g .. 3g+2  (0..26)
                const int s0 = ibase + 3 * g;
                if ((g & 1) == 0) {                  // s0 even: FA,FC even->Pa
                    TRIP(FA, Pa); LD1(FA, s0 + 3);
                    TRIP(FB, Pb); LD1(FB, s0 + 4);
                    TRIP(FC, Pa); LD1(FC, s0 + 5);
                } else {                             // s0 odd
                    TRIP(FA, Pb); LD1(FA, s0 + 3);
                    TRIP(FB, Pa); LD1(FB, s0 + 4);
                    TRIP(FC, Pb); LD1(FC, s0 + 5);
                }
            }
            TRIP(FA, Pb); LD1(FA, ibase + 30);       // s=27 (odd)
            TRIP(FB, Pa); LD1(FB, ibase + 31);       // s=28 (even)
            TRIP(FC, Pb);                            // s=29 (odd)
            TRIP(FA, Pa);                            // s=30 (even)
            TRIP(FB, Pb);                            // s=31 (odd)
            #pragma unroll
            for (int r = 0; r < 16; ++r) uacc[r] = Pa[r] + Pb[r];
        } else {
            #pragma unroll
            for (int g = 0; g < 9; ++g) {            // s = 3g .. 3g+2  (0..26)
                const int s0 = ibase + 3 * g;
                PROC1(FA, s0 + 0); LD1(FA, s0 + 3);
                PROC1(FB, s0 + 1); LD1(FB, s0 + 4);
                PROC1(FC, s0 + 2); LD1(FC, s0 + 5);
            }
            PROC1(FA, ibase + 27); LD1(FA, ibase + 30);
            PROC1(FB, ibase + 28); LD1(FB, ibase + 31);
            PROC1(FC, ibase + 29);
            PROC1(FA, ibase + 30);
            PROC1(FB, ibase + 31);
        }

        // prefetch next pass's first 3 i-tiles NOW -> latency hides under
        // the block-wide reduction/squash phase below
        if (pass < 2) {
            LD1(FA, ibase + 0);
            LD1(FB, ibase + 1);
            LD1(FC, ibase + 2);
        }

        // ---- cross-wave reduce of u (and z) over 8 waves ----
        #pragma unroll
        for (int c = 0; c < 4; ++c)
            *(float4*)(&slab[wv * 1280 + lane * 20 + c * 4]) =
                make_float4(uacc[4 * c], uacc[4 * c + 1], uacc[4 * c + 2], uacc[4 * c + 3]);
        if (pass > 0 && half == 0) zz[wv * 32 + n] = z;
        __syncthreads();

        #pragma unroll
        for (int hh = 0; hh < 2; ++hh) {
            const int e = t + hh * 512;
            const int lw = e >> 4, r = e & 15;
            float s = 0.f;
            #pragma unroll
            for (int w8 = 0; w8 < 8; ++w8) s += slab[w8 * 1280 + lw * 20 + r];
            const int nn = lw & 31, ll = (r & 3) + 8 * (r >> 2) + 4 * (lw >> 5);
            svv[nn * 33 + ll] = s;
        }
        if (t < 32) {
            if (pass == 0) zinv[t] = 1.0f / 256.0f;
            else {
                float zs = 0.f;
                #pragma unroll
                for (int w8 = 0; w8 < 8; ++w8) zs += zz[w8 * 32 + t];
                zinv[t] = 1.0f / zs;
            }
        }
        __syncthreads();

        // ---- squash (and output on last pass) ----
        {
            const int nq = t >> 4, sub = t & 15;
            const float a = svv[nq * 33 + sub] * zinv[nq];
            const float b = svv[nq * 33 + sub + 16] * zinv[nq];
            float sq = a * a + b * b;
            #pragma unroll
            for (int m = 1; m < 16; m <<= 1) sq += __shfl_xor(sq, m, 16);
            const float sc = sqrtf(sq) / (1.0f + sq);
            if (pass == 2) {
                const int ng = nh * 32 + nq;
                out[((size_t)ng * OCAPS + o) * 32 + sub] = a * sc;
                out[((size_t)ng * OCAPS + o) * 32 + sub + 16] = b * sc;
            } else {
                svv[nq * 33 + sub] = a * sc;
                svv[nq * 33 + sub + 16] = b * sc;
            }
        }
        if (pass < 2) {
            __syncthreads();
            #pragma unroll
            for (int r = 0; r < 16; ++r) {
                const int l = (r & 3) + 8 * (r >> 2) + 4 * half;
                vr[r] = svv[n * 33 + l];
            }
        }
    }
}

// ---------------- fallback (round-3 kernel, no ws needed) ----------------
#define KLEN  16
#define LLEN  32
#define TN    16
#define LGS   257
#define XROW  20
#define XIST  (TN * XROW + 4)
#define SVS   33
#define RBS   33
#define NSTG  32
#define NSTEP (ICAPS / NSTG)

__global__ __launch_bounds__(512, 2)
void caps_route_fb(const float* __restrict__ xg_all,
                   const float* __restrict__ wg_all,
                   float* __restrict__ out) {
    __shared__ float lg[TN * LGS];
    __shared__ float xt[NSTG * XIST];
    __shared__ float sv[TN * SVS];
    __shared__ float zz[8][TN];
    __shared__ float zinv[TN];

    const int t   = threadIdx.x;
    const int o   = blockIdx.x & 127;
    const int n0  = (blockIdx.x >> 7) * TN;
    const int isp = t >> 4;
    const int lb  = (t >> 2) & 3;
    const int nb  = t & 3;
    const int l0  = lb * 8;

    const float* xg = xg_all + (size_t)n0 * ICAPS * KLEN;
    const float* wg = wg_all + (size_t)o * ICAPS * KLEN * LLEN;

    for (int pass = 0; pass < 3; ++pass) {
        float u[4][8];
        float zq[4] = {0.f, 0.f, 0.f, 0.f};
        #pragma unroll
        for (int q = 0; q < 4; ++q)
            #pragma unroll
            for (int r = 0; r < 8; ++r) u[q][r] = 0.f;

        for (int st = 0; st < NSTEP; ++st) {
            const int i0 = st * NSTG;
            __syncthreads();
            #pragma unroll
            for (int j = 0; j < 4; ++j) {
                const int g   = j * 512 + t;
                const int nn  = g >> 7;
                const int rem = g & 127;
                const int il  = rem >> 2;
                const int k4c = rem & 3;
                *(float4*)(&xt[il * XIST + nn * XROW + k4c * 4]) =
                    *(const float4*)(xg + (size_t)(nn * ICAPS + i0 + il) * KLEN + k4c * 4);
            }
            __syncthreads();

            const int i = i0 + isp;
            const float* wp = wg + (size_t)i * (KLEN * LLEN) + l0;
            const float* xp = &xt[isp * XIST];
            float P[4][8];
            #pragma unroll
            for (int q = 0; q < 4; ++q)
                #pragma unroll
                for (int r = 0; r < 8; ++r) P[q][r] = 0.f;

            #pragma unroll
            for (int k4 = 0; k4 < 4; ++k4) {
                float xq[4][4];
                #pragma unroll
                for (int q = 0; q < 4; ++q)
                    *(float4*)(&xq[q][0]) = *(const float4*)(xp + (nb + 4 * q) * XROW + k4 * 4);
                #pragma unroll
                for (int kk = 0; kk < 4; ++kk) {
                    const int k = k4 * 4 + kk;
                    const float4 wa = *(const float4*)(wp + k * LLEN);
                    const float4 wb = *(const float4*)(wp + k * LLEN + 4);
                    #pragma unroll
                    for (int q = 0; q < 4; ++q) {
                        const float xv = xq[q][kk];
                        P[q][0] = fmaf(xv, wa.x, P[q][0]);
                        P[q][1] = fmaf(xv, wa.y, P[q][1]);
                        P[q][2] = fmaf(xv, wa.z, P[q][2]);
                        P[q][3] = fmaf(xv, wa.w, P[q][3]);
                        P[q][4] = fmaf(xv, wb.x, P[q][4]);
                        P[q][5] = fmaf(xv, wb.y, P[q][5]);
                        P[q][6] = fmaf(xv, wb.z, P[q][6]);
                        P[q][7] = fmaf(xv, wb.w, P[q][7]);
                    }
                }
            }

            if (pass == 0) {
                #pragma unroll
                for (int q = 0; q < 4; ++q)
                    #pragma unroll
                    for (int r = 0; r < 8; ++r) u[q][r] += P[q][r];
            } else {
                #pragma unroll
                for (int q = 0; q < 4; ++q) {
                    const float* vp = &sv[(nb + 4 * q) * SVS + l0];
                    float d = P[q][0] * vp[0] + P[q][1] * vp[1] + P[q][2] * vp[2] + P[q][3] * vp[3]
                            + P[q][4] * vp[4] + P[q][5] * vp[5] + P[q][6] * vp[6] + P[q][7] * vp[7];
                    d += __shfl_xor(d, 4);
                    d += __shfl_xor(d, 8);
                    float lnew = d;
                    if (pass == 2) lnew += lg[(nb + 4 * q) * LGS + i];
                    else if (lb == 0) lg[(nb + 4 * q) * LGS + i] = lnew;
                    const float e = __expf(lnew);
                    zq[q] += e;
                    #pragma unroll
                    for (int r = 0; r < 8; ++r) u[q][r] = fmaf(e, P[q][r], u[q][r]);
                }
            }
        }

        #pragma unroll
        for (int q = 0; q < 4; ++q) {
            #pragma unroll
            for (int r = 0; r < 8; ++r) {
                float v = u[q][r];
                v += __shfl_xor(v, 16);
                v += __shfl_xor(v, 32);
                u[q][r] = v;
            }
            float zv = zq[q];
            zv += __shfl_xor(zv, 16);
            zv += __shfl_xor(zv, 32);
            zq[q] = zv;
        }
        __syncthreads();
        {
            const int wvv = t >> 6, lane = t & 63;
            if (lane < 16) {
                float* rb = &xt[wvv * (16 * RBS) + lane * RBS];
                #pragma unroll
                for (int q = 0; q < 4; ++q)
                    #pragma unroll
                    for (int r = 0; r < 8; ++r) rb[q * 8 + r] = u[q][r];
            }
            if (pass > 0 && lane < 4) {
                #pragma unroll
                for (int q = 0; q < 4; ++q) zz[wvv][lane + 4 * q] = zq[q];
            }
        }
        __syncthreads();
        {
            const int low4 = t >> 5, qr = t & 31;
            const int qq = qr >> 3, rr = qr & 7;
            const int lbb = low4 >> 2, nbb = low4 & 3;
            float ssum = 0.f;
            #pragma unroll
            for (int w8 = 0; w8 < 8; ++w8) ssum += xt[w8 * (16 * RBS) + low4 * RBS + qr];
            sv[(nbb + 4 * qq) * SVS + lbb * 8 + rr] = ssum;
        }
        if (t < TN) {
            if (pass == 0) zinv[t] = 1.0f / 256.0f;
            else {
                float zs = 0.f;
                #pragma unroll
                for (int w8 = 0; w8 < 8; ++w8) zs += zz[w8][t];
                zinv[t] = 1.0f / zs;
            }
        }
        __syncthreads();
        {
            const int nn = t >> 5, l = t & 31;
            const float val = sv[nn * SVS + l] * zinv[nn];
            float sq = val * val;
            #pragma unroll
            for (int m = 1; m < 32; m <<= 1) sq += __shfl_xor(sq, m, 32);
            const float sc = sqrtf(sq) / (1.0f + sq);
            if (pass == 2)
                out[((size_t)(n0 + nn) * OCAPS + o) * LLEN + l] = val * sc;
            else
                sv[nn * SVS + l] = val * sc;
        }
    }
}

extern "C" void kernel_launch(void* const* d_in, const int* in_sizes, int n_in,
                              void* d_out, int out_size, void* d_ws, size_t ws_size,
                              hipStream_t stream) {
    const float* x = (const float*)d_in[0];   // [64,256,16]
    const float* w = (const float*)d_in[1];   // [128,256,16,32]
    float* outp = (float*)d_out;              // [64,128,32]
    if (ws_size >= WS_NEED) {
        caps_prep<<<dim3(4160), dim3(512), 0, stream>>>(x, w, (unsigned char*)d_ws);
        caps_main<<<dim3(256), dim3(512), 0, stream>>>((const unsigned char*)d_ws, outp);
    } else {
        caps_route_fb<<<dim3(512), dim3(512), 0, stream>>>(x, w, outp);
    }
}

// Round 6
// 197.425 us; speedup vs baseline: 2.9291x; 2.9291x over previous
//
#include <hip/hip_runtime.h>

// CapsuleLinear dynamic routing via bf16 hi/lo MFMA. N=64, I=256, O=128, K=16, L=32.
//
// Round 16 = R14 (4-named-buffer rotation, best pipeline: 131us steady even
//   WITH 124MB spill) + the real register-budget fix:
//   HIP __launch_bounds__ 2nd arg = min BLOCKS/CU (CUDA semantics). Bare
//   (512) let the compiler target 2 blocks/CU (LDS 77.5KB fits twice) ->
//   4 waves/SIMD -> 128-VGPR cap -> spill. (512,2) in R13 made it WORSE
//   (requested 2 blocks/CU explicitly). Now: __launch_bounds__(512, 1)
//   -> 2 waves/SIMD -> 256-VGPR cap; R14's ~150-reg working set fits.
//   Also pad slab stride 1280->1408 (LDS 83.2KB > 80KB) so the LDS-derived
//   occupancy agrees (grid=256=CU count; we never had 2 blocks/CU anyway).
//   Numerics identical to R10/R14 (hi/lo RNE split, 3-MFMA triple product,
//   even i -> Pa, odd -> Pb, softsteps ascending i).

#define ICAPS 256
#define OCAPS 128
#define WS_XC 67108864ull
#define WS_NEED 68157440ull
#define KPAD 20
#define SLABW 1408

typedef __attribute__((ext_vector_type(8))) short s16x8;
typedef __attribute__((ext_vector_type(16))) float f32x16;

union u4s8 { unsigned u[4]; s16x8 v; };

__device__ inline unsigned rne_adj(unsigned u) {       // bits + RNE increment
    return u + 0x7FFFu + ((u >> 16) & 1u);
}

// RNE hi/lo split of 8 fp32 -> two packed s16x8 (bf16 pairs), R4/R6 numerics.
__device__ inline void split8(const float* f, s16x8& hi, s16x8& lo) {
    u4s8 H, L;
    #pragma unroll
    for (int c = 0; c < 4; ++c) {
        const unsigned u0 = __float_as_uint(f[2 * c]);
        const unsigned u1 = __float_as_uint(f[2 * c + 1]);
        const unsigned r0 = rne_adj(u0), r1 = rne_adj(u1);
        H.u[c] = __builtin_amdgcn_perm(r1, r0, 0x07060302u);   // {hi16(r1),hi16(r0)}
        const float h0 = __uint_as_float(r0 & 0xFFFF0000u);
        const float h1 = __uint_as_float(r1 & 0xFFFF0000u);
        const unsigned l0 = rne_adj(__float_as_uint(f[2 * c] - h0));      // exact resid
        const unsigned l1 = rne_adj(__float_as_uint(f[2 * c + 1] - h1));  // then RNE
        L.u[c] = __builtin_amdgcn_perm(l1, l0, 0x07060302u);
    }
    hi = H.v; lo = L.v;
}

// ---------------- prep: coalesced read + LDS transpose + split ----------------
// w tiles: gid 0..32767 (= o*256+i); x tiles: gid 32768..33279 (= nh*256+i).
__global__ __launch_bounds__(512)
void caps_prep(const float* __restrict__ x, const float* __restrict__ w,
               unsigned char* __restrict__ ws) {
    __shared__ float T[8][32 * KPAD];     // per-wave 2.5 KB transpose buffer
    const int wv = threadIdx.x >> 6, lane = threadIdx.x & 63;
    const int gid = blockIdx.x * 8 + wv;
    float f[8];
    s16x8 hi, lo;

    if (gid < 32768) {
        // coalesced: wave reads its whole 2KB tile (512 floats) contiguously
        const float* src = w + (size_t)gid * 512 + lane * 8;
        const float4 a = *(const float4*)src;
        const float4 b = *(const float4*)(src + 4);
        const float v[8] = {a.x, a.y, a.z, a.w, b.x, b.y, b.z, b.w};
        // element j: k = lane>>2 (const), l = (lane&3)*8 + j  -> T[l][k]
        {
            float* Tw = &T[wv][0];
            const int k = lane >> 2, l0 = (lane & 3) * 8;
            #pragma unroll
            for (int j = 0; j < 8; ++j) Tw[(l0 + j) * KPAD + k] = v[j];
        }
        // T is strictly per-wave: a wave-local LDS drain suffices (no barrier).
        asm volatile("s_waitcnt lgkmcnt(0)" ::: "memory");
        // fragment read: l = lane&31, k = kb..kb+7 (contiguous -> 2x b128)
        {
            const float* rd = &T[wv][(lane & 31) * KPAD + (lane >> 5) * 8];
            const float4 ra = *(const float4*)rd;
            const float4 rb = *(const float4*)(rd + 4);
            f[0] = ra.x; f[1] = ra.y; f[2] = ra.z; f[3] = ra.w;
            f[4] = rb.x; f[5] = rb.y; f[6] = rb.z; f[7] = rb.w;
        }
        split8(f, hi, lo);
        s16x8* WC = (s16x8*)ws;
        WC[(size_t)gid * 128 + lane] = hi;        // 1KB coalesced
        WC[(size_t)gid * 128 + 64 + lane] = lo;   // 1KB coalesced
    } else if (gid < 33280) {
        const int id = gid - 32768;
        const int nh = id >> 8, i = id & 255;
        const int n = lane & 31, kb = (lane >> 5) * 8;
        const float* src = x + ((size_t)(nh * 32 + n) * ICAPS + i) * 16 + kb;
        const float4 a = *(const float4*)src;
        const float4 b = *(const float4*)(src + 4);
        f[0] = a.x; f[1] = a.y; f[2] = a.z; f[3] = a.w;
        f[4] = b.x; f[5] = b.y; f[6] = b.z; f[7] = b.w;
        split8(f, hi, lo);
        s16x8* XC = (s16x8*)(ws + WS_XC);
        XC[(size_t)id * 128 + lane] = hi;
        XC[(size_t)id * 128 + 64 + lane] = lo;
    }
}

// ---------------- main: MFMA routing, 8 waves, 4-named-buffer rotation ----------------

#define MF(a, b, c) __builtin_amdgcn_mfma_f32_32x32x16_bf16(a, b, c, 0, 0, 0)

// load ONE i-tile (4 s16x8 records = 16 VGPRs) into named regs N0..N3.
// N0 = W hi, N1 = W lo, N2 = X hi, N3 = X lo.
#define LD1(N, ii)                                   \
    {                                                \
        const size_t b_ = (size_t)(ii) * 128;        \
        N##0 = Wp[b_]; N##1 = Wp[b_ + 64];           \
        N##2 = Xp[b_]; N##3 = Xp[b_ + 64];           \
    }

// 3-MFMA triple product for one i (order identical to R10: al*bh, ah*bl, ah*bh)
#define TRIP(N, ACC)                 \
    {                                \
        ACC = MF(N##1, N##2, ACC);   \
        ACC = MF(N##0, N##3, ACC);   \
        ACC = MF(N##0, N##2, ACC);   \
    }

#define SOFTSTEP(P, ii)                                                   \
    {                                                                     \
        float da = P[0] * vr[0], db = P[8] * vr[8];                       \
        _Pragma("unroll")                                                 \
        for (int r = 1; r < 8; ++r) {                                     \
            da = fmaf(P[r], vr[r], da);                                   \
            db = fmaf(P[r + 8], vr[r + 8], db);                           \
        }                                                                 \
        float d = da + db;                                                \
        d += __shfl_xor(d, 32);                /* combine l-halves */     \
        if (pass == 1) {                                                  \
            if (half == 0) lg[(ii) * 32 + n] = d;                         \
        } else {                                                          \
            d += lg[(ii) * 32 + n];                                       \
        }                                                                 \
        const float e = __expf(d);                                        \
        z += e;                                                           \
        _Pragma("unroll")                                                 \
        for (int r = 0; r < 16; ++r) uacc[r] = fmaf(e, P[r], uacc[r]);    \
    }

// one pass>=1 step: fresh P, triple product, softmax-accumulate
#define PROC1(N, ii)                 \
    {                                \
        f32x16 P = {};               \
        TRIP(N, P);                  \
        SOFTSTEP(P, ii);             \
    }

__global__ __launch_bounds__(512, 1)
void caps_main(const unsigned char* __restrict__ ws, float* __restrict__ out) {
    __shared__ float lg[ICAPS * 32];      // [i][n] 32 KB
    __shared__ float slab[8 * SLABW];     // per-wave u partials (lane stride 20), 44KB
    __shared__ float svv[32 * 33];        // s then v
    __shared__ float zz[8 * 32];
    __shared__ float zinv[32];

    const int t = threadIdx.x, wv = t >> 6, lane = t & 63;
    const int o = blockIdx.x & 127, nh = blockIdx.x >> 7;   // o-pairs share an XCD
    const int n = lane & 31, half = lane >> 5;

    // block layout: per tile 128 s16x8 records; hi at +lane, lo at +64+lane
    const s16x8* Wp = (const s16x8*)ws + (size_t)o * ICAPS * 128 + lane;
    const s16x8* Xp = (const s16x8*)(ws + WS_XC) + (size_t)nh * ICAPS * 128 + lane;

    float vr[16];
    const int ibase = wv * 32;            // 32 i per wave = 32 steps of 1 i-tile

    // four individually-NAMED rotation buffers (16 VGPRs each; never
    // array-indexed -> guaranteed register allocation, no scratch)
    s16x8 FA0, FA1, FA2, FA3;
    s16x8 FB0, FB1, FB2, FB3;
    s16x8 FC0, FC1, FC2, FC3;
    s16x8 FD0, FD1, FD2, FD3;

    // prologue for pass 0 (subsequent passes prefetch before the reduction)
    LD1(FA, ibase + 0);
    LD1(FB, ibase + 1);
    LD1(FC, ibase + 2);
    LD1(FD, ibase + 3);

    for (int pass = 0; pass < 3; ++pass) {
        float uacc[16];
        #pragma unroll
        for (int r = 0; r < 16; ++r) uacc[r] = 0.f;
        float z = 0.f;

        if (pass == 0) {
            f32x16 Pa = {}, Pb = {};
            for (int gq = 0; gq < 8; ++gq) {
                const int iq = ibase + gq * 4;
                if (gq < 7) {
                    TRIP(FA, Pa); LD1(FA, iq + 4);
                    TRIP(FB, Pb); LD1(FB, iq + 5);
                    TRIP(FC, Pa); LD1(FC, iq + 6);
                    TRIP(FD, Pb); LD1(FD, iq + 7);
                } else {
                    TRIP(FA, Pa);
                    TRIP(FB, Pb);
                    TRIP(FC, Pa);
                    TRIP(FD, Pb);
                }
            }
            #pragma unroll
            for (int r = 0; r < 16; ++r) uacc[r] = Pa[r] + Pb[r];
        } else {
            for (int gq = 0; gq < 8; ++gq) {
                const int iq = ibase + gq * 4;
                if (gq < 7) {
                    PROC1(FA, iq + 0); LD1(FA, iq + 4);
                    PROC1(FB, iq + 1); LD1(FB, iq + 5);
                    PROC1(FC, iq + 2); LD1(FC, iq + 6);
                    PROC1(FD, iq + 3); LD1(FD, iq + 7);
                } else {
                    PROC1(FA, iq + 0);
                    PROC1(FB, iq + 1);
                    PROC1(FC, iq + 2);
                    PROC1(FD, iq + 3);
                }
            }
        }

        // prefetch next pass's first 4 i-tiles NOW -> latency hides under
        // the block-wide reduction/squash phase below
        if (pass < 2) {
            LD1(FA, ibase + 0);
            LD1(FB, ibase + 1);
            LD1(FC, ibase + 2);
            LD1(FD, ibase + 3);
        }

        // ---- cross-wave reduce of u (and z) over 8 waves ----
        #pragma unroll
        for (int c = 0; c < 4; ++c)
            *(float4*)(&slab[wv * SLABW + lane * 20 + c * 4]) =
                make_float4(uacc[4 * c], uacc[4 * c + 1], uacc[4 * c + 2], uacc[4 * c + 3]);
        if (pass > 0 && half == 0) zz[wv * 32 + n] = z;
        __syncthreads();

        #pragma unroll
        for (int hh = 0; hh < 2; ++hh) {
            const int e = t + hh * 512;
            const int lw = e >> 4, r = e & 15;
            float s = 0.f;
            #pragma unroll
            for (int w8 = 0; w8 < 8; ++w8) s += slab[w8 * SLABW + lw * 20 + r];
            const int nn = lw & 31, ll = (r & 3) + 8 * (r >> 2) + 4 * (lw >> 5);
            svv[nn * 33 + ll] = s;
        }
        if (t < 32) {
            if (pass == 0) zinv[t] = 1.0f / 256.0f;
            else {
                float zs = 0.f;
                #pragma unroll
                for (int w8 = 0; w8 < 8; ++w8) zs += zz[w8 * 32 + t];
                zinv[t] = 1.0f / zs;
            }
        }
        __syncthreads();

        // ---- squash (and output on last pass) ----
        {
            const int nq = t >> 4, sub = t & 15;
            const float a = svv[nq * 33 + sub] * zinv[nq];
            const float b = svv[nq * 33 + sub + 16] * zinv[nq];
            float sq = a * a + b * b;
            #pragma unroll
            for (int m = 1; m < 16; m <<= 1) sq += __shfl_xor(sq, m, 16);
            const float sc = sqrtf(sq) / (1.0f + sq);
            if (pass == 2) {
                const int ng = nh * 32 + nq;
                out[((size_t)ng * OCAPS + o) * 32 + sub] = a * sc;
                out[((size_t)ng * OCAPS + o) * 32 + sub + 16] = b * sc;
            } else {
                svv[nq * 33 + sub] = a * sc;
                svv[nq * 33 + sub + 16] = b * sc;
            }
        }
        if (pass < 2) {
            __syncthreads();
            #pragma unroll
            for (int r = 0; r < 16; ++r) {
                const int l = (r & 3) + 8 * (r >> 2) + 4 * half;
                vr[r] = svv[n * 33 + l];
            }
        }
    }
}

// ---------------- fallback (round-3 kernel, no ws needed) ----------------
#define KLEN  16
#define LLEN  32
#define TN    16
#define LGS   257
#define XROW  20
#define XIST  (TN * XROW + 4)
#define SVS   33
#define RBS   33
#define NSTG  32
#define NSTEP (ICAPS / NSTG)

__global__ __launch_bounds__(512, 2)
void caps_route_fb(const float* __restrict__ xg_all,
                   const float* __restrict__ wg_all,
                   float* __restrict__ out) {
    __shared__ float lg[TN * LGS];
    __shared__ float xt[NSTG * XIST];
    __shared__ float sv[TN * SVS];
    __shared__ float zz[8][TN];
    __shared__ float zinv[TN];

    const int t   = threadIdx.x;
    const int o   = blockIdx.x & 127;
    const int n0  = (blockIdx.x >> 7) * TN;
    const int isp = t >> 4;
    const int lb  = (t >> 2) & 3;
    const int nb  = t & 3;
    const int l0  = lb * 8;

    const float* xg = xg_all + (size_t)n0 * ICAPS * KLEN;
    const float* wg = wg_all + (size_t)o * ICAPS * KLEN * LLEN;

    for (int pass = 0; pass < 3; ++pass) {
        float u[4][8];
        float zq[4] = {0.f, 0.f, 0.f, 0.f};
        #pragma unroll
        for (int q = 0; q < 4; ++q)
            #pragma unroll
            for (int r = 0; r < 8; ++r) u[q][r] = 0.f;

        for (int st = 0; st < NSTEP; ++st) {
            const int i0 = st * NSTG;
            __syncthreads();
            #pragma unroll
            for (int j = 0; j < 4; ++j) {
                const int g   = j * 512 + t;
                const int nn  = g >> 7;
                const int rem = g & 127;
                const int il  = rem >> 2;
                const int k4c = rem & 3;
                *(float4*)(&xt[il * XIST + nn * XROW + k4c * 4]) =
                    *(const float4*)(xg + (size_t)(nn * ICAPS + i0 + il) * KLEN + k4c * 4);
            }
            __syncthreads();

            const int i = i0 + isp;
            const float* wp = wg + (size_t)i * (KLEN * LLEN) + l0;
            const float* xp = &xt[isp * XIST];
            float P[4][8];
            #pragma unroll
            for (int q = 0; q < 4; ++q)
                #pragma unroll
                for (int r = 0; r < 8; ++r) P[q][r] = 0.f;

            #pragma unroll
            for (int k4 = 0; k4 < 4; ++k4) {
                float xq[4][4];
                #pragma unroll
                for (int q = 0; q < 4; ++q)
                    *(float4*)(&xq[q][0]) = *(const float4*)(xp + (nb + 4 * q) * XROW + k4 * 4);
                #pragma unroll
                for (int kk = 0; kk < 4; ++kk) {
                    const int k = k4 * 4 + kk;
                    const float4 wa = *(const float4*)(wp + k * LLEN);
                    const float4 wb = *(const float4*)(wp + k * LLEN + 4);
                    #pragma unroll
                    for (int q = 0; q < 4; ++q) {
                        const float xv = xq[q][kk];
                        P[q][0] = fmaf(xv, wa.x, P[q][0]);
                        P[q][1] = fmaf(xv, wa.y, P[q][1]);
                        P[q][2] = fmaf(xv, wa.z, P[q][2]);
                        P[q][3] = fmaf(xv, wa.w, P[q][3]);
                        P[q][4] = fmaf(xv, wb.x, P[q][4]);
                        P[q][5] = fmaf(xv, wb.y, P[q][5]);
                        P[q][6] = fmaf(xv, wb.z, P[q][6]);
                        P[q][7] = fmaf(xv, wb.w, P[q][7]);
                    }
                }
            }

            if (pass == 0) {
                #pragma unroll
                for (int q = 0; q < 4; ++q)
                    #pragma unroll
                    for (int r = 0; r < 8; ++r) u[q][r] += P[q][r];
            } else {
                #pragma unroll
                for (int q = 0; q < 4; ++q) {
                    const float* vp = &sv[(nb + 4 * q) * SVS + l0];
                    float d = P[q][0] * vp[0] + P[q][1] * vp[1] + P[q][2] * vp[2] + P[q][3] * vp[3]
                            + P[q][4] * vp[4] + P[q][5] * vp[5] + P[q][6] * vp[6] + P[q][7] * vp[7];
                    d += __shfl_xor(d, 4);
                    d += __shfl_xor(d, 8);
                    float lnew = d;
                    if (pass == 2) lnew += lg[(nb + 4 * q) * LGS + i];
                    else if (lb == 0) lg[(nb + 4 * q) * LGS + i] = lnew;
                    const float e = __expf(lnew);
                    zq[q] += e;
                    #pragma unroll
                    for (int r = 0; r < 8; ++r) u[q][r] = fmaf(e, P[q][r], u[q][r]);
                }
            }
        }

        #pragma unroll
        for (int q = 0; q < 4; ++q) {
            #pragma unroll
            for (int r = 0; r < 8; ++r) {
                float v = u[q][r];
                v += __shfl_xor(v, 16);
                v += __shfl_xor(v, 32);
                u[q][r] = v;
            }
            float zv = zq[q];
            zv += __shfl_xor(zv, 16);
            zv += __shfl_xor(zv, 32);
            zq[q] = zv;
        }
        __syncthreads();
        {
            const int wvv = t >> 6, lane = t & 63;
            if (lane < 16) {
                float* rb = &xt[wvv * (16 * RBS) + lane * RBS];
                #pragma unroll
                for (int q = 0; q < 4; ++q)
                    #pragma unroll
                    for (int r = 0; r < 8; ++r) rb[q * 8 + r] = u[q][r];
            }
            if (pass > 0 && lane < 4) {
                #pragma unroll
                for (int q = 0; q < 4; ++q) zz[wvv][lane + 4 * q] = zq[q];
            }
        }
        __syncthreads();
        {
            const int low4 = t >> 5, qr = t & 31;
            const int qq = qr >> 3, rr = qr & 7;
            const int lbb = low4 >> 2, nbb = low4 & 3;
            float ssum = 0.f;
            #pragma unroll
            for (int w8 = 0; w8 < 8; ++w8) ssum += xt[w8 * (16 * RBS) + low4 * RBS + qr];
            sv[(nbb + 4 * qq) * SVS + lbb * 8 + rr] = ssum;
        }
        if (t < TN) {
            if (pass == 0) zinv[t] = 1.0f / 256.0f;
            else {
                float zs = 0.f;
                #pragma unroll
                for (int w8 = 0; w8 < 8; ++w8) zs += zz[w8][t];
                zinv[t] = 1.0f / zs;
            }
        }
        __syncthreads();
        {
            const int nn = t >> 5, l = t & 31;
            const float val = sv[nn * SVS + l] * zinv[nn];
            float sq = val * val;
            #pragma unroll
            for (int m = 1; m < 32; m <<= 1) sq += __shfl_xor(sq, m, 32);
            const float sc = sqrtf(sq) / (1.0f + sq);
            if (pass == 2)
                out[((size_t)(n0 + nn) * OCAPS + o) * LLEN + l] = val * sc;
            else
                sv[nn * SVS + l] = val * sc;
        }
    }
}

extern "C" void kernel_launch(void* const* d_in, const int* in_sizes, int n_in,
                              void* d_out, int out_size, void* d_ws, size_t ws_size,
                              hipStream_t stream) {
    const float* x = (const float*)d_in[0];   // [64,256,16]
    const float* w = (const float*)d_in[1];   // [128,256,16,32]
    float* outp = (float*)d_out;              // [64,128,32]
    if (ws_size >= WS_NEED) {
        caps_prep<<<dim3(4160), dim3(512), 0, stream>>>(x, w, (unsigned char*)d_ws);
        caps_main<<<dim3(256), dim3(512), 0, stream>>>((const unsigned char*)d_ws, outp);
    } else {
        caps_route_fb<<<dim3(512), dim3(512), 0, stream>>>(x, w, outp);
    }
}

// Round 7
// 149.999 us; speedup vs baseline: 3.8553x; 1.3162x over previous
//
#include <hip/hip_runtime.h>

// CapsuleLinear dynamic routing via bf16 hi/lo MFMA. N=64, I=256, O=128, K=16, L=32.
//
// Round 17 = 3-named-buffer rotation that FITS the 128-VGPR ceiling.
//   Evidence R13/R14/R16: 128 arch-VGPRs is a hard cap for this kernel
//   (launch_bounds(512,2)/(512,1) both ignored; gfx950 unified file likely
//   splits 256/wave into 128 arch + 128 acc once MFMA is used). 4 buffers
//   (~145 live) always spilled ~125MB. 3 buffers = ~110 live: fits.
//   R15's 3-buffer attempt failed ONLY due to '#pragma unroll' hoisting
//   ~30 loads (690MB spill); here the group loops are '#pragma unroll 1'
//   (rotation is period-1: FA/FB/FC roles are static per group) and pass 0
//   uses three fixed accumulators Pa/Pb/Pc (no parity branching), summed
//   (Pa+Pb)+Pc at the end (summation-order change is immaterial: absmax sits
//   at the bf16 hi/lo-split floor, 2^-9 tolerance vs ~2^-17 error).
//   Prefetch distance 2 steps (~360cy) x 2 waves/SIMD covers ~600cy LLC lat.
//   LDS pad (slab stride 1408 -> 83.2KB) kept from R16: guarantees 1 blk/CU.

#define ICAPS 256
#define OCAPS 128
#define WS_XC 67108864ull
#define WS_NEED 68157440ull
#define KPAD 20
#define SLABW 1408

typedef __attribute__((ext_vector_type(8))) short s16x8;
typedef __attribute__((ext_vector_type(16))) float f32x16;

union u4s8 { unsigned u[4]; s16x8 v; };

__device__ inline unsigned rne_adj(unsigned u) {       // bits + RNE increment
    return u + 0x7FFFu + ((u >> 16) & 1u);
}

// RNE hi/lo split of 8 fp32 -> two packed s16x8 (bf16 pairs), R4/R6 numerics.
__device__ inline void split8(const float* f, s16x8& hi, s16x8& lo) {
    u4s8 H, L;
    #pragma unroll
    for (int c = 0; c < 4; ++c) {
        const unsigned u0 = __float_as_uint(f[2 * c]);
        const unsigned u1 = __float_as_uint(f[2 * c + 1]);
        const unsigned r0 = rne_adj(u0), r1 = rne_adj(u1);
        H.u[c] = __builtin_amdgcn_perm(r1, r0, 0x07060302u);   // {hi16(r1),hi16(r0)}
        const float h0 = __uint_as_float(r0 & 0xFFFF0000u);
        const float h1 = __uint_as_float(r1 & 0xFFFF0000u);
        const unsigned l0 = rne_adj(__float_as_uint(f[2 * c] - h0));      // exact resid
        const unsigned l1 = rne_adj(__float_as_uint(f[2 * c + 1] - h1));  // then RNE
        L.u[c] = __builtin_amdgcn_perm(l1, l0, 0x07060302u);
    }
    hi = H.v; lo = L.v;
}

// ---------------- prep: coalesced read + LDS transpose + split ----------------
// w tiles: gid 0..32767 (= o*256+i); x tiles: gid 32768..33279 (= nh*256+i).
__global__ __launch_bounds__(512)
void caps_prep(const float* __restrict__ x, const float* __restrict__ w,
               unsigned char* __restrict__ ws) {
    __shared__ float T[8][32 * KPAD];     // per-wave 2.5 KB transpose buffer
    const int wv = threadIdx.x >> 6, lane = threadIdx.x & 63;
    const int gid = blockIdx.x * 8 + wv;
    float f[8];
    s16x8 hi, lo;

    if (gid < 32768) {
        // coalesced: wave reads its whole 2KB tile (512 floats) contiguously
        const float* src = w + (size_t)gid * 512 + lane * 8;
        const float4 a = *(const float4*)src;
        const float4 b = *(const float4*)(src + 4);
        const float v[8] = {a.x, a.y, a.z, a.w, b.x, b.y, b.z, b.w};
        // element j: k = lane>>2 (const), l = (lane&3)*8 + j  -> T[l][k]
        {
            float* Tw = &T[wv][0];
            const int k = lane >> 2, l0 = (lane & 3) * 8;
            #pragma unroll
            for (int j = 0; j < 8; ++j) Tw[(l0 + j) * KPAD + k] = v[j];
        }
        // T is strictly per-wave: a wave-local LDS drain suffices (no barrier).
        asm volatile("s_waitcnt lgkmcnt(0)" ::: "memory");
        // fragment read: l = lane&31, k = kb..kb+7 (contiguous -> 2x b128)
        {
            const float* rd = &T[wv][(lane & 31) * KPAD + (lane >> 5) * 8];
            const float4 ra = *(const float4*)rd;
            const float4 rb = *(const float4*)(rd + 4);
            f[0] = ra.x; f[1] = ra.y; f[2] = ra.z; f[3] = ra.w;
            f[4] = rb.x; f[5] = rb.y; f[6] = rb.z; f[7] = rb.w;
        }
        split8(f, hi, lo);
        s16x8* WC = (s16x8*)ws;
        WC[(size_t)gid * 128 + lane] = hi;        // 1KB coalesced
        WC[(size_t)gid * 128 + 64 + lane] = lo;   // 1KB coalesced
    } else if (gid < 33280) {
        const int id = gid - 32768;
        const int nh = id >> 8, i = id & 255;
        const int n = lane & 31, kb = (lane >> 5) * 8;
        const float* src = x + ((size_t)(nh * 32 + n) * ICAPS + i) * 16 + kb;
        const float4 a = *(const float4*)src;
        const float4 b = *(const float4*)(src + 4);
        f[0] = a.x; f[1] = a.y; f[2] = a.z; f[3] = a.w;
        f[4] = b.x; f[5] = b.y; f[6] = b.z; f[7] = b.w;
        split8(f, hi, lo);
        s16x8* XC = (s16x8*)(ws + WS_XC);
        XC[(size_t)id * 128 + lane] = hi;
        XC[(size_t)id * 128 + 64 + lane] = lo;
    }
}

// ---------------- main: MFMA routing, 8 waves, 3-named-buffer rotation ----------------

#define MF(a, b, c) __builtin_amdgcn_mfma_f32_32x32x16_bf16(a, b, c, 0, 0, 0)

// load ONE i-tile (4 s16x8 records = 16 VGPRs) into named regs N0..N3.
// N0 = W hi, N1 = W lo, N2 = X hi, N3 = X lo.
#define LD1(N, ii)                                   \
    {                                                \
        const size_t b_ = (size_t)(ii) * 128;        \
        N##0 = Wp[b_]; N##1 = Wp[b_ + 64];           \
        N##2 = Xp[b_]; N##3 = Xp[b_ + 64];           \
    }

// 3-MFMA triple product for one i (order identical to R10: al*bh, ah*bl, ah*bh)
#define TRIP(N, ACC)                 \
    {                                \
        ACC = MF(N##1, N##2, ACC);   \
        ACC = MF(N##0, N##3, ACC);   \
        ACC = MF(N##0, N##2, ACC);   \
    }

#define SOFTSTEP(P, ii)                                                   \
    {                                                                     \
        float da = P[0] * vr[0], db = P[8] * vr[8];                       \
        _Pragma("unroll")                                                 \
        for (int r = 1; r < 8; ++r) {                                     \
            da = fmaf(P[r], vr[r], da);                                   \
            db = fmaf(P[r + 8], vr[r + 8], db);                           \
        }                                                                 \
        float d = da + db;                                                \
        d += __shfl_xor(d, 32);                /* combine l-halves */     \
        if (pass == 1) {                                                  \
            if (half == 0) lg[(ii) * 32 + n] = d;                         \
        } else {                                                          \
            d += lg[(ii) * 32 + n];                                       \
        }                                                                 \
        const float e = __expf(d);                                        \
        z += e;                                                           \
        _Pragma("unroll")                                                 \
        for (int r = 0; r < 16; ++r) uacc[r] = fmaf(e, P[r], uacc[r]);    \
    }

// one pass>=1 step: fresh P, triple product, softmax-accumulate
#define PROC1(N, ii)                 \
    {                                \
        f32x16 P = {};               \
        TRIP(N, P);                  \
        SOFTSTEP(P, ii);             \
    }

__global__ __launch_bounds__(512, 1)
void caps_main(const unsigned char* __restrict__ ws, float* __restrict__ out) {
    __shared__ float lg[ICAPS * 32];      // [i][n] 32 KB
    __shared__ float slab[8 * SLABW];     // per-wave u partials (lane stride 20), 44KB
    __shared__ float svv[32 * 33];        // s then v
    __shared__ float zz[8 * 32];
    __shared__ float zinv[32];

    const int t = threadIdx.x, wv = t >> 6, lane = t & 63;
    const int o = blockIdx.x & 127, nh = blockIdx.x >> 7;   // o-pairs share an XCD
    const int n = lane & 31, half = lane >> 5;

    // block layout: per tile 128 s16x8 records; hi at +lane, lo at +64+lane
    const s16x8* Wp = (const s16x8*)ws + (size_t)o * ICAPS * 128 + lane;
    const s16x8* Xp = (const s16x8*)(ws + WS_XC) + (size_t)nh * ICAPS * 128 + lane;

    float vr[16];
    const int ibase = wv * 32;            // 32 i per wave = 32 steps of 1 i-tile

    // three individually-NAMED rotation buffers (16 VGPRs each; never
    // array-indexed -> guaranteed register allocation, no scratch)
    s16x8 FA0, FA1, FA2, FA3;
    s16x8 FB0, FB1, FB2, FB3;
    s16x8 FC0, FC1, FC2, FC3;

    // prologue for pass 0 (subsequent passes prefetch before the reduction)
    LD1(FA, ibase + 0);
    LD1(FB, ibase + 1);
    LD1(FC, ibase + 2);

    for (int pass = 0; pass < 3; ++pass) {
        float uacc[16];
        #pragma unroll
        for (int r = 0; r < 16; ++r) uacc[r] = 0.f;
        float z = 0.f;

        if (pass == 0) {
            // three fixed accumulators (buffer->acc static), summed at end
            f32x16 Pa = {}, Pb = {}, Pc = {};
            #pragma unroll 1
            for (int g = 0; g < 9; ++g) {          // steps 0..26, prefetch 3..29
                const int s0 = ibase + 3 * g;
                TRIP(FA, Pa); LD1(FA, s0 + 3);
                TRIP(FB, Pb); LD1(FB, s0 + 4);
                TRIP(FC, Pc); LD1(FC, s0 + 5);
            }
            TRIP(FA, Pa); LD1(FA, ibase + 30);     // s=27
            TRIP(FB, Pb); LD1(FB, ibase + 31);     // s=28
            TRIP(FC, Pc);                          // s=29
            TRIP(FA, Pa);                          // s=30
            TRIP(FB, Pb);                          // s=31
            #pragma unroll
            for (int r = 0; r < 16; ++r) uacc[r] = (Pa[r] + Pb[r]) + Pc[r];
        } else {
            #pragma unroll 1
            for (int g = 0; g < 9; ++g) {          // steps 0..26, prefetch 3..29
                const int s0 = ibase + 3 * g;
                PROC1(FA, s0 + 0); LD1(FA, s0 + 3);
                PROC1(FB, s0 + 1); LD1(FB, s0 + 4);
                PROC1(FC, s0 + 2); LD1(FC, s0 + 5);
            }
            PROC1(FA, ibase + 27); LD1(FA, ibase + 30);
            PROC1(FB, ibase + 28); LD1(FB, ibase + 31);
            PROC1(FC, ibase + 29);
            PROC1(FA, ibase + 30);
            PROC1(FB, ibase + 31);
        }

        // prefetch next pass's first 3 i-tiles NOW -> latency hides under
        // the block-wide reduction/squash phase below
        if (pass < 2) {
            LD1(FA, ibase + 0);
            LD1(FB, ibase + 1);
            LD1(FC, ibase + 2);
        }

        // ---- cross-wave reduce of u (and z) over 8 waves ----
        #pragma unroll
        for (int c = 0; c < 4; ++c)
            *(float4*)(&slab[wv * SLABW + lane * 20 + c * 4]) =
                make_float4(uacc[4 * c], uacc[4 * c + 1], uacc[4 * c + 2], uacc[4 * c + 3]);
        if (pass > 0 && half == 0) zz[wv * 32 + n] = z;
        __syncthreads();

        #pragma unroll
        for (int hh = 0; hh < 2; ++hh) {
            const int e = t + hh * 512;
            const int lw = e >> 4, r = e & 15;
            float s = 0.f;
            #pragma unroll
            for (int w8 = 0; w8 < 8; ++w8) s += slab[w8 * SLABW + lw * 20 + r];
            const int nn = lw & 31, ll = (r & 3) + 8 * (r >> 2) + 4 * (lw >> 5);
            svv[nn * 33 + ll] = s;
        }
        if (t < 32) {
            if (pass == 0) zinv[t] = 1.0f / 256.0f;
            else {
                float zs = 0.f;
                #pragma unroll
                for (int w8 = 0; w8 < 8; ++w8) zs += zz[w8 * 32 + t];
                zinv[t] = 1.0f / zs;
            }
        }
        __syncthreads();

        // ---- squash (and output on last pass) ----
        {
            const int nq = t >> 4, sub = t & 15;
            const float a = svv[nq * 33 + sub] * zinv[nq];
            const float b = svv[nq * 33 + sub + 16] * zinv[nq];
            float sq = a * a + b * b;
            #pragma unroll
            for (int m = 1; m < 16; m <<= 1) sq += __shfl_xor(sq, m, 16);
            const float sc = sqrtf(sq) / (1.0f + sq);
            if (pass == 2) {
                const int ng = nh * 32 + nq;
                out[((size_t)ng * OCAPS + o) * 32 + sub] = a * sc;
                out[((size_t)ng * OCAPS + o) * 32 + sub + 16] = b * sc;
            } else {
                svv[nq * 33 + sub] = a * sc;
                svv[nq * 33 + sub + 16] = b * sc;
            }
        }
        if (pass < 2) {
            __syncthreads();
            #pragma unroll
            for (int r = 0; r < 16; ++r) {
                const int l = (r & 3) + 8 * (r >> 2) + 4 * half;
                vr[r] = svv[n * 33 + l];
            }
        }
    }
}

// ---------------- fallback (round-3 kernel, no ws needed) ----------------
#define KLEN  16
#define LLEN  32
#define TN    16
#define LGS   257
#define XROW  20
#define XIST  (TN * XROW + 4)
#define SVS   33
#define RBS   33
#define NSTG  32
#define NSTEP (ICAPS / NSTG)

__global__ __launch_bounds__(512, 2)
void caps_route_fb(const float* __restrict__ xg_all,
                   const float* __restrict__ wg_all,
                   float* __restrict__ out) {
    __shared__ float lg[TN * LGS];
    __shared__ float xt[NSTG * XIST];
    __shared__ float sv[TN * SVS];
    __shared__ float zz[8][TN];
    __shared__ float zinv[TN];

    const int t   = threadIdx.x;
    const int o   = blockIdx.x & 127;
    const int n0  = (blockIdx.x >> 7) * TN;
    const int isp = t >> 4;
    const int lb  = (t >> 2) & 3;
    const int nb  = t & 3;
    const int l0  = lb * 8;

    const float* xg = xg_all + (size_t)n0 * ICAPS * KLEN;
    const float* wg = wg_all + (size_t)o * ICAPS * KLEN * LLEN;

    for (int pass = 0; pass < 3; ++pass) {
        float u[4][8];
        float zq[4] = {0.f, 0.f, 0.f, 0.f};
        #pragma unroll
        for (int q = 0; q < 4; ++q)
            #pragma unroll
            for (int r = 0; r < 8; ++r) u[q][r] = 0.f;

        for (int st = 0; st < NSTEP; ++st) {
            const int i0 = st * NSTG;
            __syncthreads();
            #pragma unroll
            for (int j = 0; j < 4; ++j) {
                const int g   = j * 512 + t;
                const int nn  = g >> 7;
                const int rem = g & 127;
                const int il  = rem >> 2;
                const int k4c = rem & 3;
                *(float4*)(&xt[il * XIST + nn * XROW + k4c * 4]) =
                    *(const float4*)(xg + (size_t)(nn * ICAPS + i0 + il) * KLEN + k4c * 4);
            }
            __syncthreads();

            const int i = i0 + isp;
            const float* wp = wg + (size_t)i * (KLEN * LLEN) + l0;
            const float* xp = &xt[isp * XIST];
            float P[4][8];
            #pragma unroll
            for (int q = 0; q < 4; ++q)
                #pragma unroll
                for (int r = 0; r < 8; ++r) P[q][r] = 0.f;

            #pragma unroll
            for (int k4 = 0; k4 < 4; ++k4) {
                float xq[4][4];
                #pragma unroll
                for (int q = 0; q < 4; ++q)
                    *(float4*)(&xq[q][0]) = *(const float4*)(xp + (nb + 4 * q) * XROW + k4 * 4);
                #pragma unroll
                for (int kk = 0; kk < 4; ++kk) {
                    const int k = k4 * 4 + kk;
                    const float4 wa = *(const float4*)(wp + k * LLEN);
                    const float4 wb = *(const float4*)(wp + k * LLEN + 4);
                    #pragma unroll
                    for (int q = 0; q < 4; ++q) {
                        const float xv = xq[q][kk];
                        P[q][0] = fmaf(xv, wa.x, P[q][0]);
                        P[q][1] = fmaf(xv, wa.y, P[q][1]);
                        P[q][2] = fmaf(xv, wa.z, P[q][2]);
                        P[q][3] = fmaf(xv, wa.w, P[q][3]);
                        P[q][4] = fmaf(xv, wb.x, P[q][4]);
                        P[q][5] = fmaf(xv, wb.y, P[q][5]);
                        P[q][6] = fmaf(xv, wb.z, P[q][6]);
                        P[q][7] = fmaf(xv, wb.w, P[q][7]);
                    }
                }
            }

            if (pass == 0) {
                #pragma unroll
                for (int q = 0; q < 4; ++q)
                    #pragma unroll
                    for (int r = 0; r < 8; ++r) u[q][r] += P[q][r];
            } else {
                #pragma unroll
                for (int q = 0; q < 4; ++q) {
                    const float* vp = &sv[(nb + 4 * q) * SVS + l0];
                    float d = P[q][0] * vp[0] + P[q][1] * vp[1] + P[q][2] * vp[2] + P[q][3] * vp[3]
                            + P[q][4] * vp[4] + P[q][5] * vp[5] + P[q][6] * vp[6] + P[q][7] * vp[7];
                    d += __shfl_xor(d, 4);
                    d += __shfl_xor(d, 8);
                    float lnew = d;
                    if (pass == 2) lnew += lg[(nb + 4 * q) * LGS + i];
                    else if (lb == 0) lg[(nb + 4 * q) * LGS + i] = lnew;
                    const float e = __expf(lnew);
                    zq[q] += e;
                    #pragma unroll
                    for (int r = 0; r < 8; ++r) u[q][r] = fmaf(e, P[q][r], u[q][r]);
                }
            }
        }

        #pragma unroll
        for (int q = 0; q < 4; ++q) {
            #pragma unroll
            for (int r = 0; r < 8; ++r) {
                float v = u[q][r];
                v += __shfl_xor(v, 16);
                v += __shfl_xor(v, 32);
                u[q][r] = v;
            }
            float zv = zq[q];
            zv += __shfl_xor(zv, 16);
            zv += __shfl_xor(zv, 32);
            zq[q] = zv;
        }
        __syncthreads();
        {
            const int wvv = t >> 6, lane = t & 63;
            if (lane < 16) {
                float* rb = &xt[wvv * (16 * RBS) + lane * RBS];
                #pragma unroll
                for (int q = 0; q < 4; ++q)
                    #pragma unroll
                    for (int r = 0; r < 8; ++r) rb[q * 8 + r] = u[q][r];
            }
            if (pass > 0 && lane < 4) {
                #pragma unroll
                for (int q = 0; q < 4; ++q) zz[wvv][lane + 4 * q] = zq[q];
            }
        }
        __syncthreads();
        {
            const int low4 = t >> 5, qr = t & 31;
            const int qq = qr >> 3, rr = qr & 7;
            const int lbb = low4 >> 2, nbb = low4 & 3;
            float ssum = 0.f;
            #pragma unroll
            for (int w8 = 0; w8 < 8; ++w8) ssum += xt[w8 * (16 * RBS) + low4 * RBS + qr];
            sv[(nbb + 4 * qq) * SVS + lbb * 8 + rr] = ssum;
        }
        if (t < TN) {
            if (pass == 0) zinv[t] = 1.0f / 256.0f;
            else {
                float zs = 0.f;
                #pragma unroll
                for (int w8 = 0; w8 < 8; ++w8) zs += zz[w8][t];
                zinv[t] = 1.0f / zs;
            }
        }
        __syncthreads();
        {
            const int nn = t >> 5, l = t & 31;
            const float val = sv[nn * SVS + l] * zinv[nn];
            float sq = val * val;
            #pragma unroll
            for (int m = 1; m < 32; m <<= 1) sq += __shfl_xor(sq, m, 32);
            const float sc = sqrtf(sq) / (1.0f + sq);
            if (pass == 2)
                out[((size_t)(n0 + nn) * OCAPS + o) * LLEN + l] = val * sc;
            else
                sv[nn * SVS + l] = val * sc;
        }
    }
}

extern "C" void kernel_launch(void* const* d_in, const int* in_sizes, int n_in,
                              void* d_out, int out_size, void* d_ws, size_t ws_size,
                              hipStream_t stream) {
    const float* x = (const float*)d_in[0];   // [64,256,16]
    const float* w = (const float*)d_in[1];   // [128,256,16,32]
    float* outp = (float*)d_out;              // [64,128,32]
    if (ws_size >= WS_NEED) {
        caps_prep<<<dim3(4160), dim3(512), 0, stream>>>(x, w, (unsigned char*)d_ws);
        caps_main<<<dim3(256), dim3(512), 0, stream>>>((const unsigned char*)d_ws, outp);
    } else {
        caps_route_fb<<<dim3(512), dim3(512), 0, stream>>>(x, w, outp);
    }
}